// Round 8
// baseline (596.794 us; speedup 1.0000x reference)
//
#include <hip/hip_runtime.h>
#include <hip/hip_cooperative_groups.h>

namespace cg = cooperative_groups;

typedef __bf16 bf16;
typedef __bf16 bf16x8 __attribute__((ext_vector_type(8)));
typedef __bf16 bf16x4 __attribute__((ext_vector_type(4)));
typedef float f32x4 __attribute__((ext_vector_type(4)));

#define SCL 0.18033688011112042f  // (1/8) * log2(e), folded into q projection

#define GLOAD_LDS16(g, l)                                          \
  __builtin_amdgcn_global_load_lds(                                \
      (const __attribute__((address_space(1))) void*)(g),          \
      (__attribute__((address_space(3))) void*)(l), 16, 0, 0)

static __device__ __forceinline__ unsigned pk_bf16(float a, float b) {
  union { bf16 h[2]; unsigned u; } cv;
  cv.h[0] = (bf16)a; cv.h[1] = (bf16)b;
  return cv.u;
}
static __device__ __forceinline__ void pl32swap(unsigned& a, unsigned& b) {
  auto r = __builtin_amdgcn_permlane32_swap(a, b, false, false);
  a = r[0]; b = r[1];
}
static __device__ __forceinline__ void pl16swap(unsigned& a, unsigned& b) {
  auto r = __builtin_amdgcn_permlane16_swap(a, b, false, false);
  a = r[0]; b = r[1];
}

// ---------------------------------------------------------------------------
// 128x64-tile GEMM core (proven) — used by outproj.
// ---------------------------------------------------------------------------
__device__ __forceinline__ void gemm128x64_core(const bf16* __restrict__ A,
                                                const bf16* __restrict__ Bt,
                                                int m0, int n0,
                                                bf16* As, bf16* Bs,
                                                f32x4 (&acc)[4][2],
                                                int wave, int lane) {
  const int l15 = lane & 15, quad = lane >> 4;
  const int psw = l15 & 7;
  const int lrow = lane >> 3;
  const int gchunk = (lane & 7) ^ lrow;
  const bf16* Ag = A + (size_t)(m0 + wave * 32 + lrow) * 512 + gchunk * 8;
  const bf16* Bg = Bt + (size_t)(n0 + wave * 16 + lrow) * 512 + gchunk * 8;
  bf16* Asw = As + wave * 32 * 64;
  bf16* Bsw = Bs + wave * 16 * 64;
  const int wm = (wave >> 1) * 64, wn = (wave & 1) * 32;

#pragma unroll
  for (int g = 0; g < 4; g++)
    GLOAD_LDS16(Ag + (size_t)(g * 8) * 512, Asw + g * 8 * 64);
#pragma unroll
  for (int g = 0; g < 2; g++)
    GLOAD_LDS16(Bg + (size_t)(g * 8) * 512, Bsw + g * 8 * 64);
  __syncthreads();

  for (int t = 0; t < 8; t++) {
    if (t < 7) {
      const int kt = (t + 1) * 64;
      const int nb = (t + 1) & 1;
#pragma unroll
      for (int g = 0; g < 4; g++)
        GLOAD_LDS16(Ag + kt + (size_t)(g * 8) * 512, Asw + nb * (128 * 64) + g * 8 * 64);
#pragma unroll
      for (int g = 0; g < 2; g++)
        GLOAD_LDS16(Bg + kt + (size_t)(g * 8) * 512, Bsw + nb * (64 * 64) + g * 8 * 64);
    }
    const bf16* Ac = As + (t & 1) * (128 * 64);
    const bf16* Bc = Bs + (t & 1) * (64 * 64);
#pragma unroll
    for (int h = 0; h < 2; h++) {
      bf16x8 af[4], bfr[2];
#pragma unroll
      for (int i = 0; i < 4; i++)
        af[i] = *(const bf16x8*)&Ac[(wm + i * 16 + l15) * 64 + (((h * 4 + quad) ^ psw) * 8)];
#pragma unroll
      for (int j = 0; j < 2; j++)
        bfr[j] = *(const bf16x8*)&Bc[(wn + j * 16 + l15) * 64 + (((h * 4 + quad) ^ psw) * 8)];
#pragma unroll
      for (int i = 0; i < 4; i++)
#pragma unroll
        for (int j = 0; j < 2; j++)
          acc[i][j] = __builtin_amdgcn_mfma_f32_16x16x32_bf16(af[i], bfr[j], acc[i][j], 0, 0, 0);
    }
    __syncthreads();
  }
}

// ---------------------------------------------------------------------------
// 128x128-tile GEMM core (R7) — used by proj.
// ---------------------------------------------------------------------------
__device__ __forceinline__ void gemm128x128_core(const bf16* __restrict__ A,
                                                 const bf16* __restrict__ Bt,
                                                 int m0, int n0,
                                                 bf16* As, bf16* Bs,
                                                 f32x4 (&acc)[4][4],
                                                 int wave, int lane) {
  const int l15 = lane & 15, quad = lane >> 4;
  const int psw = l15 & 7;
  const int lrow = lane >> 3;
  const int gchunk = (lane & 7) ^ lrow;
  const bf16* Ag = A + (size_t)(m0 + wave * 32 + lrow) * 512 + gchunk * 8;
  const bf16* Bg = Bt + (size_t)(n0 + wave * 32 + lrow) * 512 + gchunk * 8;
  bf16* Asw = As + wave * 32 * 64;
  bf16* Bsw = Bs + wave * 32 * 64;
  const int wm = (wave >> 1) * 64, wn = (wave & 1) * 64;

#pragma unroll
  for (int g = 0; g < 4; g++) {
    GLOAD_LDS16(Ag + (size_t)(g * 8) * 512, Asw + g * 8 * 64);
    GLOAD_LDS16(Bg + (size_t)(g * 8) * 512, Bsw + g * 8 * 64);
  }
  __syncthreads();

  for (int t = 0; t < 8; t++) {
    if (t < 7) {
      const int kt = (t + 1) * 64;
      const int nb = (t + 1) & 1;
#pragma unroll
      for (int g = 0; g < 4; g++) {
        GLOAD_LDS16(Ag + kt + (size_t)(g * 8) * 512, Asw + nb * (128 * 64) + g * 8 * 64);
        GLOAD_LDS16(Bg + kt + (size_t)(g * 8) * 512, Bsw + nb * (128 * 64) + g * 8 * 64);
      }
    }
    const bf16* Ac = As + (t & 1) * (128 * 64);
    const bf16* Bc = Bs + (t & 1) * (128 * 64);
#pragma unroll
    for (int h = 0; h < 2; h++) {
      bf16x8 af[4], bfr[4];
#pragma unroll
      for (int i = 0; i < 4; i++)
        af[i] = *(const bf16x8*)&Ac[(wm + i * 16 + l15) * 64 + (((h * 4 + quad) ^ psw) * 8)];
#pragma unroll
      for (int j = 0; j < 4; j++)
        bfr[j] = *(const bf16x8*)&Bc[(wn + j * 16 + l15) * 64 + (((h * 4 + quad) ^ psw) * 8)];
#pragma unroll
      for (int i = 0; i < 4; i++)
#pragma unroll
        for (int j = 0; j < 4; j++)
          acc[i][j] = __builtin_amdgcn_mfma_f32_16x16x32_bf16(af[i], bfr[j], acc[i][j], 0, 0, 0);
    }
    __syncthreads();
  }
}

// ---------------------------------------------------------------------------
// Phase bodies as device functions (shared by mega kernel and fallbacks).
// ---------------------------------------------------------------------------
__device__ __forceinline__ void prep_body(int bid, int tid, char* smem,
                                          const float* x, const float* ctx,
                                          const float* Wq, const float* Wkv,
                                          const float* Wo,
                                          bf16* xb, bf16* cb,
                                          bf16* Wqt, bf16* Wkvt, bf16* Wot) {
  // x: 2048 chunks of 2048 elems; 4 per block
#pragma unroll
  for (int k = 0; k < 4; k++) {
    size_t i = ((size_t)bid * 4 + k) * 2048 + (size_t)tid * 8;
    float4 a0 = *(const float4*)&x[i];
    float4 a1 = *(const float4*)&x[i + 4];
    bf16x8 o;
    o[0] = (bf16)a0.x; o[1] = (bf16)a0.y; o[2] = (bf16)a0.z; o[3] = (bf16)a0.w;
    o[4] = (bf16)a1.x; o[5] = (bf16)a1.y; o[6] = (bf16)a1.z; o[7] = (bf16)a1.w;
    *(bf16x8*)&xb[i] = o;
  }
  // ctx: 1024 chunks; 2 per block
#pragma unroll
  for (int k = 0; k < 2; k++) {
    size_t i = ((size_t)bid * 2 + k) * 2048 + (size_t)tid * 8;
    float4 a0 = *(const float4*)&ctx[i];
    float4 a1 = *(const float4*)&ctx[i + 4];
    bf16x8 o;
    o[0] = (bf16)a0.x; o[1] = (bf16)a0.y; o[2] = (bf16)a0.z; o[3] = (bf16)a0.w;
    o[4] = (bf16)a1.x; o[5] = (bf16)a1.y; o[6] = (bf16)a1.z; o[7] = (bf16)a1.w;
    *(bf16x8*)&cb[i] = o;
  }
  // weight transposes: 1024 32x32 tiles; 2 per block
  float (*tile)[33] = (float(*)[33])smem;
  const int j = tid & 31, i0 = tid >> 5;
  for (int k = 0; k < 2; k++) {
    const int idx = bid * 2 + k;
    const int bx = idx & 63;
    const int k0 = (idx >> 6) * 32;
    const float* W; bf16* Wt; int N, n0;
    if (bx < 16)      { W = Wq;  Wt = Wqt;  N = 512;  n0 = bx * 32; }
    else if (bx < 48) { W = Wkv; Wt = Wkvt; N = 1024; n0 = (bx - 16) * 32; }
    else              { W = Wo;  Wt = Wot;  N = 512;  n0 = (bx - 48) * 32; }
    __syncthreads();
#pragma unroll
    for (int ii = 0; ii < 4; ii++) {
      int i = i0 * 4 + ii;
      tile[i][j] = W[(size_t)(k0 + i) * N + n0 + j];
    }
    __syncthreads();
#pragma unroll
    for (int ii = 0; ii < 4; ii++) {
      int i = i0 * 4 + ii;
      Wt[(size_t)(n0 + i) * 512 + k0 + j] = (bf16)tile[j][i];
    }
  }
}

__device__ __forceinline__ void proj_body(int bid, int tid, char* smem,
                                          const bf16* xb, const bf16* cb,
                                          const bf16* Wqt, const bf16* Wkvt,
                                          bf16* qb, bf16* Kb, bf16* Vtb) {
  bf16* As = (bf16*)smem;
  bf16* Bs = As + 2 * 128 * 64;
  const int wave = tid >> 6, lane = tid & 63;
  const int quad = lane >> 4, l15 = lane & 15;
  f32x4 acc[4][4] = {};
  const int wm = (wave >> 1) * 64, wn = (wave & 1) * 64;

  if (bid < 256) {
    const int m0 = (bid & 63) * 128, n0 = (bid >> 6) * 128;  // XCD: bid%8==m%8
    gemm128x128_core(xb, Wqt, m0, n0, As, Bs, acc, wave, lane);
#pragma unroll
    for (int i = 0; i < 4; i++) {
      const int rowb = m0 + wm + i * 16 + quad * 4;
#pragma unroll
      for (int j = 0; j < 4; j++) {
        const int col = n0 + wn + j * 16 + l15;
#pragma unroll
        for (int r = 0; r < 4; r++)
          qb[(size_t)(rowb + r) * 512 + col] = (bf16)(acc[i][j][r] * SCL);
      }
    }
  } else {
    const int idx = bid - 256;
    const int m0 = (idx & 31) * 128, n0 = (idx >> 5) * 128;
    gemm128x128_core(cb, Wkvt, m0, n0, As, Bs, acc, wave, lane);
#pragma unroll
    for (int i = 0; i < 4; i++) {
      const int rowb = m0 + wm + i * 16 + quad * 4;
#pragma unroll
      for (int j = 0; j < 4; j++) {
        const int col = n0 + wn + j * 16 + l15;
        if (col < 512) {
#pragma unroll
          for (int r = 0; r < 4; r++)
            Kb[(size_t)(rowb + r) * 512 + col] = (bf16)acc[i][j][r];
        } else {
          const int hh = (col - 512) >> 6, d = (col - 512) & 63;
          const int bb = rowb >> 11, mb = rowb & 2047;
          bf16x4 pk;
          pk[0] = (bf16)acc[i][j][0]; pk[1] = (bf16)acc[i][j][1];
          pk[2] = (bf16)acc[i][j][2]; pk[3] = (bf16)acc[i][j][3];
          *(bf16x4*)&Vtb[((size_t)(bb * 8 + hh) * 64 + d) * 2048 + mb] = pk;
        }
      }
    }
  }
}

__device__ __forceinline__ void attn_body(int bid, int tid, char* smem,
                                          const bf16* q, const bf16* Kb,
                                          const bf16* Vtb, bf16* attn_out) {
  const int wave = tid >> 6, lane = tid & 63;
  const int quad = lane >> 4, l15 = lane & 15;
  const int g = bid & 15, inner = bid >> 4;
  const int b = g >> 3, h = g & 7;
  const int s = inner & 3, nt = inner >> 2;
  const int n0 = nt * 128;

  bf16* Kl0 = (bf16*)smem;         // [2][64*64]
  bf16* Vl0 = Kl0 + 2 * 64 * 64;   // [2][64*64]

  size_t qoff[2];
  bf16x8 qf[2][2];
#pragma unroll
  for (int cg2 = 0; cg2 < 2; cg2++) {
    const int n = n0 + wave * 32 + cg2 * 16 + l15;
    qoff[cg2] = ((size_t)((b * 1024 + n) * 4 + s)) * 512 + h * 64;
    qf[cg2][0] = *(const bf16x8*)&q[qoff[cg2] + quad * 8];
    qf[cg2][1] = *(const bf16x8*)&q[qoff[cg2] + 32 + quad * 8];
  }

  f32x4 o[2][4] = {};
  f32x4 ol[2] = {};
  bf16x8 ones;
#pragma unroll
  for (int i = 0; i < 8; i++) ones[i] = (bf16)1.0f;

  const int srow = tid >> 2, c0 = tid & 3;
  const bf16* Kg = Kb + (size_t)(b * 2048 + srow) * 512 + h * 64 + c0 * 16;
  const bf16* Vg = Vtb + ((size_t)(b * 8 + h) * 64 + srow) * 2048 + c0 * 16;
  const int ssw = srow & 7;
  const int koff0 = srow * 64 + ((c0 * 2) ^ ssw) * 8;
  const int koff1 = srow * 64 + ((c0 * 2 + 1) ^ ssw) * 8;

  uint4 kr0 = *(const uint4*)Kg;
  uint4 kr1 = *(const uint4*)(Kg + 8);
  uint4 vr0 = *(const uint4*)Vg;
  uint4 vr1 = *(const uint4*)(Vg + 8);
  __syncthreads();  // smem handoff from previous phase
  *(uint4*)&Kl0[koff0] = kr0; *(uint4*)&Kl0[koff1] = kr1;
  *(uint4*)&Vl0[koff0] = vr0; *(uint4*)&Vl0[koff1] = vr1;

  const int psw = l15 & 7;

  for (int t = 0; t < 32; ++t) {
    __syncthreads();
    if (t < 31) {
      const bf16* kg = Kg + (size_t)(t + 1) * 64 * 512;
      const bf16* vg = Vg + (t + 1) * 64;
      kr0 = *(const uint4*)kg; kr1 = *(const uint4*)(kg + 8);
      vr0 = *(const uint4*)vg; vr1 = *(const uint4*)(vg + 8);
    }
    const bf16* Kc = Kl0 + (t & 1) * (64 * 64);
    const bf16* Vc = Vl0 + (t & 1) * (64 * 64);

    __builtin_amdgcn_s_setprio(1);

    f32x4 sf[2][4];
#pragma unroll
    for (int mc = 0; mc < 4; mc++) {
      bf16x8 kf0 = *(const bf16x8*)&Kc[(mc * 16 + l15) * 64 + ((quad ^ psw) * 8)];
      bf16x8 kf1 = *(const bf16x8*)&Kc[(mc * 16 + l15) * 64 + (((4 + quad) ^ psw) * 8)];
#pragma unroll
      for (int cg2 = 0; cg2 < 2; cg2++) {
        f32x4 z = {};
        z = __builtin_amdgcn_mfma_f32_16x16x32_bf16(kf0, qf[cg2][0], z, 0, 0, 0);
        z = __builtin_amdgcn_mfma_f32_16x16x32_bf16(kf1, qf[cg2][1], z, 0, 0, 0);
        sf[cg2][mc] = z;
      }
    }

    unsigned w[2][4][2];
#pragma unroll
    for (int cg2 = 0; cg2 < 2; cg2++)
#pragma unroll
      for (int mc = 0; mc < 4; mc++) {
        const float e0 = __builtin_amdgcn_exp2f(sf[cg2][mc][0]);
        const float e1 = __builtin_amdgcn_exp2f(sf[cg2][mc][1]);
        const float e2 = __builtin_amdgcn_exp2f(sf[cg2][mc][2]);
        const float e3 = __builtin_amdgcn_exp2f(sf[cg2][mc][3]);
        w[cg2][mc][0] = pk_bf16(e0, e1);
        w[cg2][mc][1] = pk_bf16(e2, e3);
      }

    bf16x8 pf[2][2];
#pragma unroll
    for (int cg2 = 0; cg2 < 2; cg2++)
#pragma unroll
      for (int mch = 0; mch < 2; mch++) {
        unsigned tw0, tw1, tw2, tw3;
        {
          unsigned a = w[cg2][2 * mch][0], bb2 = w[cg2][2 * mch + 1][0];
          pl32swap(a, bb2);
          pl16swap(a, bb2);
          tw0 = a; tw2 = bb2;
        }
        {
          unsigned a = w[cg2][2 * mch][1], bb2 = w[cg2][2 * mch + 1][1];
          pl32swap(a, bb2);
          pl16swap(a, bb2);
          tw1 = a; tw3 = bb2;
        }
        union { unsigned u[4]; bf16x8 v; } cv;
        cv.u[0] = tw0; cv.u[1] = tw1; cv.u[2] = tw2; cv.u[3] = tw3;
        pf[mch][cg2] = cv.v;
      }

#pragma unroll
    for (int mch = 0; mch < 2; mch++) {
#pragma unroll
      for (int dg = 0; dg < 4; dg++) {
        bf16x8 vf = *(const bf16x8*)&Vc[(dg * 16 + l15) * 64 + (((mch * 4 + quad) ^ psw)) * 8];
#pragma unroll
        for (int cg2 = 0; cg2 < 2; cg2++)
          o[cg2][dg] = __builtin_amdgcn_mfma_f32_16x16x32_bf16(vf, pf[mch][cg2], o[cg2][dg], 0, 0, 0);
      }
#pragma unroll
      for (int cg2 = 0; cg2 < 2; cg2++)
        ol[cg2] = __builtin_amdgcn_mfma_f32_16x16x32_bf16(ones, pf[mch][cg2], ol[cg2], 0, 0, 0);
    }

    __builtin_amdgcn_s_setprio(0);

    if (t < 31) {
      bf16* Kn = Kl0 + ((t + 1) & 1) * (64 * 64);
      bf16* Vn = Vl0 + ((t + 1) & 1) * (64 * 64);
      *(uint4*)&Kn[koff0] = kr0; *(uint4*)&Kn[koff1] = kr1;
      *(uint4*)&Vn[koff0] = vr0; *(uint4*)&Vn[koff1] = vr1;
    }
  }

#pragma unroll
  for (int cg2 = 0; cg2 < 2; cg2++) {
    const float inv = 1.0f / ol[cg2][0];
#pragma unroll
    for (int dg = 0; dg < 4; dg++) {
      bf16x4 ok;
      ok[0] = (bf16)(o[cg2][dg][0] * inv); ok[1] = (bf16)(o[cg2][dg][1] * inv);
      ok[2] = (bf16)(o[cg2][dg][2] * inv); ok[3] = (bf16)(o[cg2][dg][3] * inv);
      *(bf16x4*)&attn_out[qoff[cg2] + dg * 16 + quad * 4] = ok;
    }
  }
}

__device__ __forceinline__ void outproj_body(int bid, int tid, char* smem,
                                             const bf16* attn, const bf16* Wot,
                                             float* out, const float* bias) {
  bf16* As = (bf16*)smem;
  bf16* Bs = As + 2 * 128 * 64;
  const int wave = tid >> 6, lane = tid & 63;
  const int quad = lane >> 4, l15 = lane & 15;
  const int m0 = (bid & 63) * 128, n0 = (bid >> 6) * 64;
  f32x4 acc[4][2] = {};
  gemm128x64_core(attn, Wot, m0, n0, As, Bs, acc, wave, lane);
  const int wm = (wave >> 1) * 64, wn = (wave & 1) * 32;
#pragma unroll
  for (int i = 0; i < 4; i++) {
    const int rowb = m0 + wm + i * 16 + quad * 4;
#pragma unroll
    for (int j = 0; j < 2; j++) {
      const int col = n0 + wn + j * 16 + l15;
      const float bv = bias[col];
#pragma unroll
      for (int r = 0; r < 4; r++)
        out[(size_t)(rowb + r) * 512 + col] = acc[i][j][r] + bv;
    }
  }
}

// ---------------------------------------------------------------------------
// Cooperative mega-kernel: prep -> proj -> attn -> outproj with grid syncs.
// 512 blocks x 256 threads = exactly 2 blocks/CU co-resident. 64 KB LDS.
// ---------------------------------------------------------------------------
__global__ __launch_bounds__(256, 2) void mega_kernel(
    const float* __restrict__ x, const float* __restrict__ ctx,
    const float* __restrict__ Wq, const float* __restrict__ Wkv,
    const float* __restrict__ Wo, const float* __restrict__ bo,
    bf16* __restrict__ xb, bf16* __restrict__ cb, bf16* __restrict__ qb,
    bf16* __restrict__ Kb, bf16* __restrict__ Vtb,
    bf16* __restrict__ Wqt, bf16* __restrict__ Wkvt, bf16* __restrict__ Wot,
    float* __restrict__ out) {
  __shared__ __align__(16) char smem[65536];
  cg::grid_group grid = cg::this_grid();
  const int tid = threadIdx.x;
  const int bid = blockIdx.x;

  prep_body(bid, tid, smem, x, ctx, Wq, Wkv, Wo, xb, cb, Wqt, Wkvt, Wot);
  __threadfence();
  grid.sync();
  __threadfence();

  proj_body(bid, tid, smem, xb, cb, Wqt, Wkvt, qb, Kb, Vtb);
  __threadfence();
  grid.sync();
  __threadfence();

  attn_body(bid, tid, smem, qb, Kb, Vtb, xb /* attn out reuses xb */);
  __threadfence();
  grid.sync();
  __threadfence();

  outproj_body(bid, tid, smem, xb, Wot, out, bo);
}

// ---------------------------------------------------------------------------
// Fallback standalone kernels (proven R2/R7 structure), used only if the
// cooperative launch is rejected.
// ---------------------------------------------------------------------------
__global__ __launch_bounds__(256) void prep_kernel(const float* __restrict__ x,
                                                   const float* __restrict__ ctx,
                                                   const float* __restrict__ Wq,
                                                   const float* __restrict__ Wkv,
                                                   const float* __restrict__ Wo,
                                                   bf16* __restrict__ xb,
                                                   bf16* __restrict__ cb,
                                                   bf16* __restrict__ Wqt,
                                                   bf16* __restrict__ Wkvt,
                                                   bf16* __restrict__ Wot) {
  __shared__ __align__(16) char smem[4352];
  prep_body(blockIdx.x, threadIdx.x, smem, x, ctx, Wq, Wkv, Wo, xb, cb, Wqt, Wkvt, Wot);
}

__global__ __launch_bounds__(256, 2) void proj_kernel(const bf16* __restrict__ xb,
                                                      const bf16* __restrict__ cb,
                                                      const bf16* __restrict__ Wqt,
                                                      const bf16* __restrict__ Wkvt,
                                                      bf16* __restrict__ qb,
                                                      bf16* __restrict__ Kb,
                                                      bf16* __restrict__ Vtb) {
  __shared__ __align__(16) char smem[65536];
  proj_body(blockIdx.x, threadIdx.x, smem, xb, cb, Wqt, Wkvt, qb, Kb, Vtb);
}

__global__ __launch_bounds__(256, 2) void attn_kernel(const bf16* __restrict__ q,
                                                      const bf16* __restrict__ Kb,
                                                      const bf16* __restrict__ Vtb,
                                                      bf16* __restrict__ attn_out) {
  __shared__ __align__(16) char smem[32768];
  attn_body(blockIdx.x, threadIdx.x, smem, q, Kb, Vtb, attn_out);
}

__global__ __launch_bounds__(256, 2) void outproj_kernel(const bf16* __restrict__ attn,
                                                         const bf16* __restrict__ Wot,
                                                         float* __restrict__ out,
                                                         const float* __restrict__ bias) {
  __shared__ __align__(16) char smem[49152];
  outproj_body(blockIdx.x, threadIdx.x, smem, attn, Wot, out, bias);
}

// ---------------------------------------------------------------------------
extern "C" void kernel_launch(void* const* d_in, const int* in_sizes, int n_in,
                              void* d_out, int out_size, void* d_ws, size_t ws_size,
                              hipStream_t stream) {
  const float* x = (const float*)d_in[0];
  const float* context = (const float*)d_in[1];
  const float* Wq = (const float*)d_in[2];
  const float* Wkv = (const float*)d_in[3];
  const float* Wo = (const float*)d_in[4];
  const float* bo = (const float*)d_in[5];
  float* out = (float*)d_out;

  char* ws = (char*)d_ws;
  bf16* xb   = (bf16*)(ws);                         // 8 MB (reused as attn out)
  bf16* cb   = (bf16*)(ws + (8u << 20));            // 4 MB
  bf16* qb   = (bf16*)(ws + (12u << 20));           // 8 MB
  bf16* Kb   = (bf16*)(ws + (20u << 20));           // 4 MB
  bf16* Vtb  = (bf16*)(ws + (24u << 20));           // 4 MB
  bf16* Wqt  = (bf16*)(ws + (28u << 20));           // 512 KB
  bf16* Wkvt = (bf16*)(ws + (28u << 20) + 524288);  // 1 MB
  bf16* Wot  = (bf16*)(ws + (28u << 20) + 1572864); // 512 KB

  void* args[] = {(void*)&x, (void*)&context, (void*)&Wq, (void*)&Wkv,
                  (void*)&Wo, (void*)&bo, (void*)&xb, (void*)&cb, (void*)&qb,
                  (void*)&Kb, (void*)&Vtb, (void*)&Wqt, (void*)&Wkvt,
                  (void*)&Wot, (void*)&out};
  hipError_t err = hipLaunchCooperativeKernel(
      reinterpret_cast<const void*>(mega_kernel), dim3(512), dim3(256),
      args, 0, stream);
  if (err != hipSuccess) {
    // Fallback: proven 4-kernel sequence (R7 configuration).
    prep_kernel<<<512, 256, 0, stream>>>(x, context, Wq, Wkv, Wo, xb, cb, Wqt, Wkvt, Wot);
    proj_kernel<<<512, 256, 0, stream>>>(xb, cb, Wqt, Wkvt, qb, Kb, Vtb);
    attn_kernel<<<512, 256, 0, stream>>>(qb, Kb, Vtb, xb);
    outproj_kernel<<<512, 256, 0, stream>>>(xb, Wot, out, bo);
  }
}

// Round 9
// 150.653 us; speedup vs baseline: 3.9614x; 3.9614x over previous
//
#include <hip/hip_runtime.h>

typedef __bf16 bf16;
typedef __bf16 bf16x8 __attribute__((ext_vector_type(8)));
typedef __bf16 bf16x4 __attribute__((ext_vector_type(4)));
typedef float f32x4 __attribute__((ext_vector_type(4)));

#define SCL 0.18033688011112042f  // (1/8) * log2(e), folded into q projection

#define GLOAD_LDS16(g, l)                                          \
  __builtin_amdgcn_global_load_lds(                                \
      (const __attribute__((address_space(1))) void*)(g),          \
      (__attribute__((address_space(3))) void*)(l), 16, 0, 0)

// packed bf16 pair: lo16 = bf16(a), hi16 = bf16(b).
static __device__ __forceinline__ unsigned pk_bf16(float a, float b) {
  union { bf16 h[2]; unsigned u; } cv;
  cv.h[0] = (bf16)a; cv.h[1] = (bf16)b;
  return cv.u;
}
static __device__ __forceinline__ void pl32swap(unsigned& a, unsigned& b) {
  auto r = __builtin_amdgcn_permlane32_swap(a, b, false, false);
  a = r[0]; b = r[1];
}
static __device__ __forceinline__ void pl16swap(unsigned& a, unsigned& b) {
  auto r = __builtin_amdgcn_permlane16_swap(a, b, false, false);
  a = r[0]; b = r[1];
}

// ---------------------------------------------------------------------------
// Fused prep: fp32->bf16 convert of x (blocks 0-2047) and context
// (2048-3071), plus weight transposes (blocks 3072-4095).
// ---------------------------------------------------------------------------
__global__ __launch_bounds__(256) void prep_kernel(const float* __restrict__ x,
                                                   const float* __restrict__ ctx,
                                                   const float* __restrict__ Wq,
                                                   const float* __restrict__ Wkv,
                                                   const float* __restrict__ Wo,
                                                   bf16* __restrict__ xb,
                                                   bf16* __restrict__ cb,
                                                   bf16* __restrict__ Wqt,
                                                   bf16* __restrict__ Wkvt,
                                                   bf16* __restrict__ Wot) {
  const int bid = blockIdx.x;
  const int tid = threadIdx.x;
  if (bid < 3072) {
    const float* src;
    bf16* dst;
    size_t off;
    if (bid < 2048) { src = x; dst = xb; off = (size_t)bid * 2048; }
    else            { src = ctx; dst = cb; off = (size_t)(bid - 2048) * 2048; }
    size_t i = off + (size_t)tid * 8;
    float4 a0 = *(const float4*)&src[i];
    float4 a1 = *(const float4*)&src[i + 4];
    bf16x8 o;
    o[0] = (bf16)a0.x; o[1] = (bf16)a0.y; o[2] = (bf16)a0.z; o[3] = (bf16)a0.w;
    o[4] = (bf16)a1.x; o[5] = (bf16)a1.y; o[6] = (bf16)a1.z; o[7] = (bf16)a1.w;
    *(bf16x8*)&dst[i] = o;
  } else {
    __shared__ float tile[32][33];
    const int idx = bid - 3072;
    const int bx = idx & 63;
    const int k0 = (idx >> 6) * 32;
    const float* W; bf16* Wt; int N, n0;
    if (bx < 16)      { W = Wq;  Wt = Wqt;  N = 512;  n0 = bx * 32; }
    else if (bx < 48) { W = Wkv; Wt = Wkvt; N = 1024; n0 = (bx - 16) * 32; }
    else              { W = Wo;  Wt = Wot;  N = 512;  n0 = (bx - 48) * 32; }
    const int j = tid & 31, i0 = tid >> 5;
#pragma unroll
    for (int ii = 0; ii < 4; ii++) {
      int i = i0 * 4 + ii;
      tile[i][j] = W[(size_t)(k0 + i) * N + n0 + j];
    }
    __syncthreads();
#pragma unroll
    for (int ii = 0; ii < 4; ii++) {
      int i = i0 * 4 + ii;
      Wt[(size_t)(n0 + i) * 512 + k0 + j] = (bf16)tile[j][i];
    }
  }
}

// ---------------------------------------------------------------------------
// 128x64-tile GEMM core (proven) — used by outproj.
// ---------------------------------------------------------------------------
__device__ __forceinline__ void gemm128x64_core(const bf16* __restrict__ A,
                                                const bf16* __restrict__ Bt,
                                                int m0, int n0,
                                                bf16* As, bf16* Bs,
                                                f32x4 (&acc)[4][2],
                                                int wave, int lane) {
  const int l15 = lane & 15, quad = lane >> 4;
  const int psw = l15 & 7;
  const int lrow = lane >> 3;            // 0..7
  const int gchunk = (lane & 7) ^ lrow;  // swizzled source 16B-chunk
  const bf16* Ag = A + (size_t)(m0 + wave * 32 + lrow) * 512 + gchunk * 8;
  const bf16* Bg = Bt + (size_t)(n0 + wave * 16 + lrow) * 512 + gchunk * 8;
  bf16* Asw = As + wave * 32 * 64;
  bf16* Bsw = Bs + wave * 16 * 64;
  const int wm = (wave >> 1) * 64, wn = (wave & 1) * 32;

#pragma unroll
  for (int g = 0; g < 4; g++)
    GLOAD_LDS16(Ag + (size_t)(g * 8) * 512, Asw + g * 8 * 64);
#pragma unroll
  for (int g = 0; g < 2; g++)
    GLOAD_LDS16(Bg + (size_t)(g * 8) * 512, Bsw + g * 8 * 64);
  __syncthreads();

  for (int t = 0; t < 8; t++) {
    if (t < 7) {
      const int kt = (t + 1) * 64;
      const int nb = (t + 1) & 1;
#pragma unroll
      for (int g = 0; g < 4; g++)
        GLOAD_LDS16(Ag + kt + (size_t)(g * 8) * 512, Asw + nb * (128 * 64) + g * 8 * 64);
#pragma unroll
      for (int g = 0; g < 2; g++)
        GLOAD_LDS16(Bg + kt + (size_t)(g * 8) * 512, Bsw + nb * (64 * 64) + g * 8 * 64);
    }
    const bf16* Ac = As + (t & 1) * (128 * 64);
    const bf16* Bc = Bs + (t & 1) * (64 * 64);
#pragma unroll
    for (int h = 0; h < 2; h++) {
      bf16x8 af[4], bfr[2];
#pragma unroll
      for (int i = 0; i < 4; i++)
        af[i] = *(const bf16x8*)&Ac[(wm + i * 16 + l15) * 64 + (((h * 4 + quad) ^ psw) * 8)];
#pragma unroll
      for (int j = 0; j < 2; j++)
        bfr[j] = *(const bf16x8*)&Bc[(wn + j * 16 + l15) * 64 + (((h * 4 + quad) ^ psw) * 8)];
#pragma unroll
      for (int i = 0; i < 4; i++)
#pragma unroll
        for (int j = 0; j < 2; j++)
          acc[i][j] = __builtin_amdgcn_mfma_f32_16x16x32_bf16(af[i], bfr[j], acc[i][j], 0, 0, 0);
    }
    __syncthreads();
  }
}

// ---------------------------------------------------------------------------
// 128x128-tile GEMM core. Wave tile 64x64, acc[4][4]. B staged like A.
// MFMA:ds_read ratio 2.0 vs 1.33 for 128x64. 64KB LDS -> 2 blocks/CU.
// ---------------------------------------------------------------------------
__device__ __forceinline__ void gemm128x128_core(const bf16* __restrict__ A,
                                                 const bf16* __restrict__ Bt,
                                                 int m0, int n0,
                                                 bf16* As, bf16* Bs,
                                                 f32x4 (&acc)[4][4],
                                                 int wave, int lane) {
  const int l15 = lane & 15, quad = lane >> 4;
  const int psw = l15 & 7;
  const int lrow = lane >> 3;            // 0..7
  const int gchunk = (lane & 7) ^ lrow;  // swizzled source 16B-chunk
  const bf16* Ag = A + (size_t)(m0 + wave * 32 + lrow) * 512 + gchunk * 8;
  const bf16* Bg = Bt + (size_t)(n0 + wave * 32 + lrow) * 512 + gchunk * 8;
  bf16* Asw = As + wave * 32 * 64;
  bf16* Bsw = Bs + wave * 32 * 64;
  const int wm = (wave >> 1) * 64, wn = (wave & 1) * 64;

#pragma unroll
  for (int g = 0; g < 4; g++) {
    GLOAD_LDS16(Ag + (size_t)(g * 8) * 512, Asw + g * 8 * 64);
    GLOAD_LDS16(Bg + (size_t)(g * 8) * 512, Bsw + g * 8 * 64);
  }
  __syncthreads();

  for (int t = 0; t < 8; t++) {
    if (t < 7) {  // issue next-tile staging first (overlaps with compute)
      const int kt = (t + 1) * 64;
      const int nb = (t + 1) & 1;
#pragma unroll
      for (int g = 0; g < 4; g++) {
        GLOAD_LDS16(Ag + kt + (size_t)(g * 8) * 512, Asw + nb * (128 * 64) + g * 8 * 64);
        GLOAD_LDS16(Bg + kt + (size_t)(g * 8) * 512, Bsw + nb * (128 * 64) + g * 8 * 64);
      }
    }
    const bf16* Ac = As + (t & 1) * (128 * 64);
    const bf16* Bc = Bs + (t & 1) * (128 * 64);
#pragma unroll
    for (int h = 0; h < 2; h++) {
      bf16x8 af[4], bfr[4];
#pragma unroll
      for (int i = 0; i < 4; i++)
        af[i] = *(const bf16x8*)&Ac[(wm + i * 16 + l15) * 64 + (((h * 4 + quad) ^ psw) * 8)];
#pragma unroll
      for (int j = 0; j < 4; j++)
        bfr[j] = *(const bf16x8*)&Bc[(wn + j * 16 + l15) * 64 + (((h * 4 + quad) ^ psw) * 8)];
#pragma unroll
      for (int i = 0; i < 4; i++)
#pragma unroll
        for (int j = 0; j < 4; j++)
          acc[i][j] = __builtin_amdgcn_mfma_f32_16x16x32_bf16(af[i], bfr[j], acc[i][j], 0, 0, 0);
    }
    __syncthreads();
  }
}

// ---------------------------------------------------------------------------
// Fused q-proj + kv-proj, 128x128 tiles, 512 blocks, XCD-aware mapping.
// blocks 0-255: q-proj (64 m-tiles x 2 n-tiles... 4 n-tiles of 128);
// 256-511: kv (32 m x 8 n).
// ---------------------------------------------------------------------------
__global__ __launch_bounds__(256, 2) void proj_kernel(const bf16* __restrict__ xb,
                                                      const bf16* __restrict__ cb,
                                                      const bf16* __restrict__ Wqt,
                                                      const bf16* __restrict__ Wkvt,
                                                      bf16* __restrict__ qb,
                                                      bf16* __restrict__ Kb,
                                                      bf16* __restrict__ Vtb) {
  __shared__ __align__(16) bf16 As[2 * 128 * 64];
  __shared__ __align__(16) bf16 Bs[2 * 128 * 64];
  const int tid = threadIdx.x;
  const int wave = tid >> 6, lane = tid & 63;
  const int quad = lane >> 4, l15 = lane & 15;
  const int bid = blockIdx.x;
  f32x4 acc[4][4] = {};
  const int wm = (wave >> 1) * 64, wn = (wave & 1) * 64;

  if (bid < 256) {
    const int m0 = (bid & 63) * 128, n0 = (bid >> 6) * 128;  // XCD: bid%8 == m%8
    gemm128x128_core(xb, Wqt, m0, n0, As, Bs, acc, wave, lane);
#pragma unroll
    for (int i = 0; i < 4; i++) {
      const int rowb = m0 + wm + i * 16 + quad * 4;
#pragma unroll
      for (int j = 0; j < 4; j++) {
        const int col = n0 + wn + j * 16 + l15;
#pragma unroll
        for (int r = 0; r < 4; r++)
          qb[(size_t)(rowb + r) * 512 + col] = (bf16)(acc[i][j][r] * SCL);
      }
    }
  } else {
    const int idx = bid - 256;
    const int m0 = (idx & 31) * 128, n0 = (idx >> 5) * 128;  // XCD: bid%8 == m%8
    gemm128x128_core(cb, Wkvt, m0, n0, As, Bs, acc, wave, lane);
#pragma unroll
    for (int i = 0; i < 4; i++) {
      const int rowb = m0 + wm + i * 16 + quad * 4;
#pragma unroll
      for (int j = 0; j < 4; j++) {
        const int col = n0 + wn + j * 16 + l15;
        if (col < 512) {
#pragma unroll
          for (int r = 0; r < 4; r++)
            Kb[(size_t)(rowb + r) * 512 + col] = (bf16)acc[i][j][r];
        } else {
          const int hh = (col - 512) >> 6, d = (col - 512) & 63;
          const int bb = rowb >> 11, mb = rowb & 2047;
          bf16x4 pk;
          pk[0] = (bf16)acc[i][j][0]; pk[1] = (bf16)acc[i][j][1];
          pk[2] = (bf16)acc[i][j][2]; pk[3] = (bf16)acc[i][j][3];
          *(bf16x4*)&Vtb[((size_t)(bb * 8 + hh) * 64 + d) * 2048 + mb] = pk;
        }
      }
    }
  }
}

// ---------------------------------------------------------------------------
// Final projection: out = attn @ Wot^T + bo, fp32. 512 blocks, XCD-mapped.
// ---------------------------------------------------------------------------
__global__ __launch_bounds__(256, 2) void outproj_kernel(const bf16* __restrict__ attn,
                                                         const bf16* __restrict__ Wot,
                                                         float* __restrict__ out,
                                                         const float* __restrict__ bias) {
  __shared__ __align__(16) bf16 As[2 * 128 * 64];
  __shared__ __align__(16) bf16 Bs[2 * 64 * 64];
  const int tid = threadIdx.x;
  const int wave = tid >> 6, lane = tid & 63;
  const int quad = lane >> 4, l15 = lane & 15;
  const int bid = blockIdx.x;
  const int m0 = (bid & 63) * 128, n0 = (bid >> 6) * 64;
  f32x4 acc[4][2] = {};
  gemm128x64_core(attn, Wot, m0, n0, As, Bs, acc, wave, lane);
  const int wm = (wave >> 1) * 64, wn = (wave & 1) * 32;
#pragma unroll
  for (int i = 0; i < 4; i++) {
    const int rowb = m0 + wm + i * 16 + quad * 4;
#pragma unroll
    for (int j = 0; j < 2; j++) {
      const int col = n0 + wn + j * 16 + l15;
      const float bv = bias[col];
#pragma unroll
      for (int r = 0; r < 4; r++)
        out[(size_t)(rowb + r) * 512 + col] = acc[i][j][r] + bv;
    }
  }
}

// ---------------------------------------------------------------------------
// Flash attention — best measured structure (48.7 µs).
// Sᵀ formulation, in-register P exchange (pk + permlane32/16_swap),
// K AND V LDS double-buffered, register-prefetched one tile ahead.
// no-max softmax; l via ones-row MFMA. setprio(1) over compute.
// ---------------------------------------------------------------------------
__global__ __launch_bounds__(256, 2) void attn_kernel(const bf16* __restrict__ q,
                                                      const bf16* __restrict__ Kb,
                                                      const bf16* __restrict__ Vtb,
                                                      bf16* __restrict__ attn_out) {
  const int tid = threadIdx.x;
  const int wave = tid >> 6, lane = tid & 63;
  const int quad = lane >> 4, l15 = lane & 15;
  const int bid = blockIdx.x;
  // XCD grouping: same (b,h) -> same bid mod 16 -> same XCD (mod 8)
  const int g = bid & 15, inner = bid >> 4;   // inner in [0,32)
  const int b = g >> 3, h = g & 7;
  const int s = inner & 3, nt = inner >> 2;   // nt in [0,8)
  const int n0 = nt * 128;

  __shared__ __align__(16) bf16 Kl[2][64 * 64];
  __shared__ __align__(16) bf16 Vl[2][64 * 64];

  // Q B-fragments for the wave's two 16-col groups (SCL pre-applied)
  size_t qoff[2];
  bf16x8 qf[2][2];
#pragma unroll
  for (int cg = 0; cg < 2; cg++) {
    const int n = n0 + wave * 32 + cg * 16 + l15;
    qoff[cg] = ((size_t)((b * 1024 + n) * 4 + s)) * 512 + h * 64;
    qf[cg][0] = *(const bf16x8*)&q[qoff[cg] + quad * 8];
    qf[cg][1] = *(const bf16x8*)&q[qoff[cg] + 32 + quad * 8];
  }

  f32x4 o[2][4] = {};
  f32x4 ol[2] = {};
  bf16x8 ones;
#pragma unroll
  for (int i = 0; i < 8; i++) ones[i] = (bf16)1.0f;

  // staging: thread -> row (tid>>2), 16B chunks 2*(tid&3), 2*(tid&3)+1
  const int srow = tid >> 2, c0 = tid & 3;
  const bf16* Kg = Kb + (size_t)(b * 2048 + srow) * 512 + h * 64 + c0 * 16;
  const bf16* Vg = Vtb + ((size_t)(b * 8 + h) * 64 + srow) * 2048 + c0 * 16;
  const int ssw = srow & 7;
  const int koff0 = srow * 64 + ((c0 * 2) ^ ssw) * 8;
  const int koff1 = srow * 64 + ((c0 * 2 + 1) ^ ssw) * 8;

  uint4 kr0 = *(const uint4*)Kg;
  uint4 kr1 = *(const uint4*)(Kg + 8);
  uint4 vr0 = *(const uint4*)Vg;
  uint4 vr1 = *(const uint4*)(Vg + 8);
  *(uint4*)&Kl[0][koff0] = kr0; *(uint4*)&Kl[0][koff1] = kr1;
  *(uint4*)&Vl[0][koff0] = vr0; *(uint4*)&Vl[0][koff1] = vr1;

  const int psw = l15 & 7;

  for (int t = 0; t < 32; ++t) {
    __syncthreads();
    if (t < 31) {
      const bf16* kg = Kg + (size_t)(t + 1) * 64 * 512;
      const bf16* vg = Vg + (t + 1) * 64;
      kr0 = *(const uint4*)kg; kr1 = *(const uint4*)(kg + 8);
      vr0 = *(const uint4*)vg; vr1 = *(const uint4*)(vg + 8);
    }
    const bf16* Kc = &Kl[t & 1][0];
    const bf16* Vc = &Vl[t & 1][0];

    __builtin_amdgcn_s_setprio(1);

    // Sᵀ: sf[cg][mc][r] = Sᵀ[m = mc*16+quad*4+r][n-group cg]  (exp2 domain)
    f32x4 sf[2][4];
#pragma unroll
    for (int mc = 0; mc < 4; mc++) {
      bf16x8 kf0 = *(const bf16x8*)&Kc[(mc * 16 + l15) * 64 + ((quad ^ psw) * 8)];
      bf16x8 kf1 = *(const bf16x8*)&Kc[(mc * 16 + l15) * 64 + (((4 + quad) ^ psw) * 8)];
#pragma unroll
      for (int cg = 0; cg < 2; cg++) {
        f32x4 z = {};
        z = __builtin_amdgcn_mfma_f32_16x16x32_bf16(kf0, qf[cg][0], z, 0, 0, 0);
        z = __builtin_amdgcn_mfma_f32_16x16x32_bf16(kf1, qf[cg][1], z, 0, 0, 0);
        sf[cg][mc] = z;
      }
    }

    // exp2 numerators -> packed bf16-pair words (in registers, no LDS)
    unsigned w[2][4][2];  // [cg][mc][j]: lo = p[2j], hi = p[2j+1]
#pragma unroll
    for (int cg = 0; cg < 2; cg++)
#pragma unroll
      for (int mc = 0; mc < 4; mc++) {
        const float e0 = __builtin_amdgcn_exp2f(sf[cg][mc][0]);
        const float e1 = __builtin_amdgcn_exp2f(sf[cg][mc][1]);
        const float e2 = __builtin_amdgcn_exp2f(sf[cg][mc][2]);
        const float e3 = __builtin_amdgcn_exp2f(sf[cg][mc][3]);
        w[cg][mc][0] = pk_bf16(e0, e1);
        w[cg][mc][1] = pk_bf16(e2, e3);
      }

    // in-register quad exchange: C-layout -> PV B-fragments
    bf16x8 pf[2][2];  // [mch][cg]
#pragma unroll
    for (int cg = 0; cg < 2; cg++)
#pragma unroll
      for (int mch = 0; mch < 2; mch++) {
        unsigned tw0, tw1, tw2, tw3;
        {
          unsigned a = w[cg][2 * mch][0], bb2 = w[cg][2 * mch + 1][0];
          pl32swap(a, bb2);
          pl16swap(a, bb2);
          tw0 = a; tw2 = bb2;
        }
        {
          unsigned a = w[cg][2 * mch][1], bb2 = w[cg][2 * mch + 1][1];
          pl32swap(a, bb2);
          pl16swap(a, bb2);
          tw1 = a; tw3 = bb2;
        }
        union { unsigned u[4]; bf16x8 v; } cv;
        cv.u[0] = tw0; cv.u[1] = tw1; cv.u[2] = tw2; cv.u[3] = tw3;
        pf[mch][cg] = cv.v;
      }

    // Oᵀ += Vᵀ·Pᵀ ; l += 1ᵀ·Pᵀ (ones-row MFMA)
#pragma unroll
    for (int mch = 0; mch < 2; mch++) {
#pragma unroll
      for (int dg = 0; dg < 4; dg++) {
        bf16x8 vf = *(const bf16x8*)&Vc[(dg * 16 + l15) * 64 + (((mch * 4 + quad) ^ psw)) * 8];
#pragma unroll
        for (int cg = 0; cg < 2; cg++)
          o[cg][dg] = __builtin_amdgcn_mfma_f32_16x16x32_bf16(vf, pf[mch][cg], o[cg][dg], 0, 0, 0);
      }
#pragma unroll
      for (int cg = 0; cg < 2; cg++)
        ol[cg] = __builtin_amdgcn_mfma_f32_16x16x32_bf16(ones, pf[mch][cg], ol[cg], 0, 0, 0);
    }

    __builtin_amdgcn_s_setprio(0);

    // stage tile t+1 into the other LDS buffer
    if (t < 31) {
      bf16* Kn = &Kl[(t + 1) & 1][0];
      bf16* Vn = &Vl[(t + 1) & 1][0];
      *(uint4*)&Kn[koff0] = kr0; *(uint4*)&Kn[koff1] = kr1;
      *(uint4*)&Vn[koff0] = vr0; *(uint4*)&Vn[koff1] = vr1;
    }
  }

  // epilogue: l[n] = any row of ol[cg]; normalize, pack 8B stores
#pragma unroll
  for (int cg = 0; cg < 2; cg++) {
    const float inv = 1.0f / ol[cg][0];
#pragma unroll
    for (int dg = 0; dg < 4; dg++) {
      bf16x4 ok;
      ok[0] = (bf16)(o[cg][dg][0] * inv); ok[1] = (bf16)(o[cg][dg][1] * inv);
      ok[2] = (bf16)(o[cg][dg][2] * inv); ok[3] = (bf16)(o[cg][dg][3] * inv);
      *(bf16x4*)&attn_out[qoff[cg] + dg * 16 + quad * 4] = ok;
    }
  }
}

// ---------------------------------------------------------------------------
extern "C" void kernel_launch(void* const* d_in, const int* in_sizes, int n_in,
                              void* d_out, int out_size, void* d_ws, size_t ws_size,
                              hipStream_t stream) {
  const float* x = (const float*)d_in[0];
  const float* context = (const float*)d_in[1];
  const float* Wq = (const float*)d_in[2];
  const float* Wkv = (const float*)d_in[3];
  const float* Wo = (const float*)d_in[4];
  const float* bo = (const float*)d_in[5];
  float* out = (float*)d_out;

  char* ws = (char*)d_ws;
  bf16* xb   = (bf16*)(ws);                         // 8 MB (reused as attn)
  bf16* cb   = (bf16*)(ws + (8u << 20));            // 4 MB
  bf16* qb   = (bf16*)(ws + (12u << 20));           // 8 MB
  bf16* Kb   = (bf16*)(ws + (20u << 20));           // 4 MB
  bf16* Vtb  = (bf16*)(ws + (24u << 20));           // 4 MB
  bf16* Wqt  = (bf16*)(ws + (28u << 20));           // 512 KB
  bf16* Wkvt = (bf16*)(ws + (28u << 20) + 524288);  // 1 MB
  bf16* Wot  = (bf16*)(ws + (28u << 20) + 1572864); // 512 KB
  bf16* attn = xb;  // xb dead after q-proj

  prep_kernel<<<4096, 256, 0, stream>>>(x, context, Wq, Wkv, Wo, xb, cb, Wqt, Wkvt, Wot);
  proj_kernel<<<512, 256, 0, stream>>>(xb, cb, Wqt, Wkvt, qb, Kb, Vtb);
  attn_kernel<<<512, 256, 0, stream>>>(qb, Kb, Vtb, attn);
  outproj_kernel<<<512, 256, 0, stream>>>(attn, Wot, out, bo);
}